// Round 3
// baseline (7976.842 us; speedup 1.0000x reference)
//
#include <hip/hip_runtime.h>
#include <hip/hip_fp16.h>
#include <cstdint>

// ---------------- sizes ----------------
#define NUM_WORDS 4096
#define MAX_CHARS 16
#define CE 10
#define NF 32
#define WE 250
#define HID 250
#define IN_DIM 282      // 32 + 250
#define KPAD 288        // padded IN_DIM
#define NGATE 1000      // 4*HID
#define NPAD 1024       // padded gate rows
#define TAGS 50

typedef _Float16 half2v __attribute__((ext_vector_type(2)));

#ifndef __has_builtin
#define __has_builtin(x) 0
#endif

__device__ __forceinline__ float dot2acc(uint32_t w, uint32_t h, float acc) {
#if __has_builtin(__builtin_amdgcn_fdot2)
  return __builtin_amdgcn_fdot2(__builtin_bit_cast(half2v, w),
                                __builtin_bit_cast(half2v, h), acc, false);
#else
  half2v wv = __builtin_bit_cast(half2v, w);
  half2v hv = __builtin_bit_cast(half2v, h);
  return acc + (float)wv.x * (float)hv.x + (float)wv.y * (float)hv.y;
#endif
}

__device__ __forceinline__ uint64_t AL(const uint64_t* p) {
  return __hip_atomic_load(p, __ATOMIC_RELAXED, __HIP_MEMORY_SCOPE_AGENT);
}
__device__ __forceinline__ void AS(uint64_t* p, uint64_t v) {
  __hip_atomic_store(p, v, __ATOMIC_RELAXED, __HIP_MEMORY_SCOPE_AGENT);
}

// ---------------- prep kernels ----------------
__global__ void prep_wt(const float* __restrict__ wih, float* __restrict__ wt) {
  int idx = blockIdx.x * 256 + threadIdx.x;           // over [KPAD][NPAD]
  if (idx >= KPAD * NPAD) return;
  int k = idx >> 10, j = idx & (NPAD - 1);
  wt[idx] = (j < NGATE && k < IN_DIM) ? wih[j * IN_DIM + k] : 0.0f;
}

__global__ void prep_bsum(const float* __restrict__ bih, const float* __restrict__ bhh,
                          float* __restrict__ bsum) {
  int j = blockIdx.x * 256 + threadIdx.x;
  if (j >= NPAD) return;
  bsum[j] = (j < NGATE) ? bih[j] + bhh[j] : 0.0f;
}

// w_hh [1000][250] f32 -> f16x2, layout wpack[g][c][T]: row j = 250*g + T, cols 2c,2c+1
__global__ void prep_whh4(const float* __restrict__ whh, uint32_t* __restrict__ wpack) {
  int idx = blockIdx.x * 256 + threadIdx.x;   // over 4*128*256
  if (idx >= 4 * 128 * 256) return;
  int T = idx & 255, c = (idx >> 8) & 127, g = idx >> 15;
  int j = 250 * g + T;
  int c0 = 2 * c, c1 = 2 * c + 1;
  float f0 = (T < 250 && c0 < HID) ? whh[j * HID + c0] : 0.0f;
  float f1 = (T < 250 && c1 < HID) ? whh[j * HID + c1] : 0.0f;
  uint32_t lo = (uint32_t)__half_as_ushort(__float2half(f0));
  uint32_t hi = (uint32_t)__half_as_ushort(__float2half(f1));
  wpack[idx] = lo | (hi << 16);
}

__global__ void prep_dwt(const float* __restrict__ dw, float* __restrict__ dwt) {
  int idx = blockIdx.x * 256 + threadIdx.x;    // over [HID][64]
  if (idx >= HID * 64) return;
  int k = idx >> 6, l = idx & 63;
  dwt[idx] = (l < TAGS) ? dw[l * HID + k] : 0.0f;
}

// ---------------- feature kernel: char CNN + word emb -> x[4096][288] ----------------
__global__ void feat_kernel(const int* __restrict__ ci, const int* __restrict__ wi,
                            const float* __restrict__ cemb, const float* __restrict__ wemb,
                            const float* __restrict__ convw, const float* __restrict__ convb,
                            float* __restrict__ x) {
  int w = blockIdx.x;
  int t = threadIdx.x;  // 64
  __shared__ float ce[MAX_CHARS][CE];
  __shared__ float cw[NF * CE * 3];
  for (int i = t; i < MAX_CHARS * CE; i += 64) {
    int ch = i / CE, d = i % CE;
    ce[ch][d] = cemb[ci[w * MAX_CHARS + ch] * CE + d];
  }
  for (int i = t; i < NF * CE * 3; i += 64) cw[i] = convw[i];
  __syncthreads();

  int f = t & 31, hf = t >> 5;
  float mx = -1e30f;
  for (int p = hf * 8; p < hf * 8 + 8; ++p) {
    float s = 0.0f;
    for (int kk = 0; kk < 3; ++kk) {
      int cp = p + kk - 1;
      if (cp < 0 || cp > 15) continue;
      for (int d = 0; d < CE; ++d) s = fmaf(ce[cp][d], cw[f * 30 + d * 3 + kk], s);
    }
    mx = fmaxf(mx, s);
  }
  float other = __shfl_xor(mx, 32, 64);
  mx = fmaxf(mx, other) + convb[f];
  if (t < 32) x[(size_t)w * KPAD + f] = mx;

  int widx = wi[w];
  for (int d = t; d < WE; d += 64) x[(size_t)w * KPAD + 32 + d] = wemb[(size_t)widx * WE + d];
  if (t < KPAD - IN_DIM) x[(size_t)w * KPAD + IN_DIM + t] = 0.0f;
}

// ---------------- pre-gate GEMM: pre[4096][1024] = x[4096][288] * wt[288][1024] + bsum ----
#define GBM 64
#define GBN 64
#define GBK 16
__global__ __launch_bounds__(256) void gemm_pre(const float* __restrict__ x,
                                                const float* __restrict__ wt,
                                                const float* __restrict__ bsum,
                                                float* __restrict__ pre) {
  __shared__ float As[GBK][GBM];
  __shared__ float Bs[GBK][GBN];
  int tid = threadIdx.x;
  int m0 = blockIdx.y * GBM, n0 = blockIdx.x * GBN;
  int tx = tid & 15, ty = tid >> 4;
  float acc[4][4] = {};
  for (int k0 = 0; k0 < KPAD; k0 += GBK) {
    {
      int r = tid >> 2, cq = (tid & 3) * 4;
      float4 av = *(const float4*)(x + (size_t)(m0 + r) * KPAD + k0 + cq);
      As[cq + 0][r] = av.x; As[cq + 1][r] = av.y; As[cq + 2][r] = av.z; As[cq + 3][r] = av.w;
    }
    {
      int r = tid >> 4, c = (tid & 15) * 4;
      float4 bv = *(const float4*)(wt + (size_t)(k0 + r) * NPAD + n0 + c);
      *(float4*)&Bs[r][c] = bv;
    }
    __syncthreads();
#pragma unroll
    for (int k = 0; k < GBK; ++k) {
      float a[4], b[4];
#pragma unroll
      for (int i = 0; i < 4; ++i) a[i] = As[k][ty * 4 + i];
#pragma unroll
      for (int j = 0; j < 4; ++j) b[j] = Bs[k][tx * 4 + j];
#pragma unroll
      for (int i = 0; i < 4; ++i)
#pragma unroll
        for (int j = 0; j < 4; ++j) acc[i][j] = fmaf(a[i], b[j], acc[i][j]);
    }
    __syncthreads();
  }
#pragma unroll
  for (int i = 0; i < 4; ++i) {
    int m = m0 + ty * 4 + i;
#pragma unroll
    for (int j = 0; j < 4; ++j) {
      int n = n0 + tx * 4 + j;
      pre[(size_t)m * NPAD + n] = acc[i][j] + bsum[n];
    }
  }
}

// ---------------- 4-block LSTM: block g owns gate type g (rows 250g..250g+249) ----------
// 256 threads, 1 gate row each, 128 weight u32 VGPR-resident (launch_bounds(256,1) ->
// 512-reg budget, no AGPR pressure). Per step: dot -> act -> tagged 8B agent-atomic
// store -> poll-gather other 3 gates -> redundant c/h update -> LDS h2 (double-buffered).
__global__ __launch_bounds__(256, 1) void lstm4(const uint32_t* __restrict__ wpack,
                                                const float* __restrict__ pre,
                                                uint64_t* __restrict__ gx,
                                                float* __restrict__ hs) {
  __shared__ uint32_t s_h2[2][128];   // f16x2 h, double-buffered by step parity
  const int g = blockIdx.x;
  const int T = threadIdx.x;
  const bool active = (T < HID);
  const int row = 250 * g + T;

  uint32_t w[128];
#pragma unroll
  for (int c = 0; c < 128; ++c) w[c] = wpack[(g * 128 + c) * 256 + T];

  if (T < 128) { s_h2[0][T] = 0u; s_h2[1][T] = 0u; }
  float cst = 0.0f;
  __syncthreads();

  const bool is_tanh = (g == 2);
  float pv = pre[(size_t)0 * NPAD + row];

#pragma unroll 1
  for (int t = 0; t < NUM_WORDS; ++t) {
    const int p2 = t & 1;
    const uint32_t tag = (uint32_t)(t + 1);
    float p = pv;
    if (t + 1 < NUM_WORDS) pv = pre[(size_t)(t + 1) * NPAD + row];

    // ---- gate dot: a = pre + w_hh[row] . h ----
    float a0 = 0.0f, a1 = 0.0f, a2 = 0.0f, a3 = 0.0f;
    const uint4* h2v = (const uint4*)s_h2[p2];
#pragma unroll
    for (int q = 0; q < 32; ++q) {
      uint4 hv = h2v[q];
      a0 = dot2acc(w[4 * q + 0], hv.x, a0);
      a1 = dot2acc(w[4 * q + 1], hv.y, a1);
      a2 = dot2acc(w[4 * q + 2], hv.z, a2);
      a3 = dot2acc(w[4 * q + 3], hv.w, a3);
    }
    float a = p + ((a0 + a1) + (a2 + a3));

    // ---- activation (uniform per block) ----
    float z = __expf(is_tanh ? 2.0f * a : -a);
    float inv = 1.0f / (1.0f + z);
    float act = is_tanh ? 1.0f - 2.0f * inv : inv;

    // ---- publish own gate (tag packed with value: self-validating) ----
    uint64_t* gbuf = gx + (size_t)p2 * NPAD;
    if (active) AS(&gbuf[row], ((uint64_t)tag << 32) | (uint64_t)__float_as_uint(act));

    // ---- gather all 4 gates for hidden unit T ----
    float h = 0.0f;
    if (active) {
      uint64_t v0 = 0, v1 = 0, v2 = 0, v3 = 0;
      if (g != 0) v0 = AL(&gbuf[T]);
      if (g != 1) v1 = AL(&gbuf[250 + T]);
      if (g != 2) v2 = AL(&gbuf[500 + T]);
      if (g != 3) v3 = AL(&gbuf[750 + T]);
      if (g != 0) while ((uint32_t)(v0 >> 32) != tag) v0 = AL(&gbuf[T]);
      if (g != 1) while ((uint32_t)(v1 >> 32) != tag) v1 = AL(&gbuf[250 + T]);
      if (g != 2) while ((uint32_t)(v2 >> 32) != tag) v2 = AL(&gbuf[500 + T]);
      if (g != 3) while ((uint32_t)(v3 >> 32) != tag) v3 = AL(&gbuf[750 + T]);
      float gi = (g == 0) ? act : __uint_as_float((uint32_t)v0);
      float gf = (g == 1) ? act : __uint_as_float((uint32_t)v1);
      float gg = (g == 2) ? act : __uint_as_float((uint32_t)v2);
      float go = (g == 3) ? act : __uint_as_float((uint32_t)v3);
      cst = gf * cst + gi * gg;
      float z2 = __expf(2.0f * cst);
      float th = 1.0f - 2.0f / (1.0f + z2);
      h = go * th;
      if (g == 0) hs[(size_t)t * 256 + T] = h;
      ((__half*)s_h2[1 - p2])[T] = __float2half(h);
    }
    __syncthreads();   // h2[1-p2] complete before next step reads it
  }
}

// ---------------- dense + log_softmax ----------------
__global__ __launch_bounds__(256) void dense_kernel(const float* __restrict__ hs,
                                                    const float* __restrict__ dwt,
                                                    const float* __restrict__ db,
                                                    float* __restrict__ out) {
  int t = blockIdx.x * 4 + (threadIdx.x >> 6);
  int l = threadIdx.x & 63;
  float acc = 0.0f;
  for (int k = 0; k < HID; ++k) acc = fmaf(hs[(size_t)t * 256 + k], dwt[k * 64 + l], acc);
  float logit = acc + ((l < TAGS) ? db[l] : 0.0f);
  float val = (l < TAGS) ? logit : -1e30f;
  float m = val;
#pragma unroll
  for (int off = 32; off; off >>= 1) m = fmaxf(m, __shfl_xor(m, off, 64));
  float e = (l < TAGS) ? __expf(logit - m) : 0.0f;
  float s = e;
#pragma unroll
  for (int off = 32; off; off >>= 1) s += __shfl_xor(s, off, 64);
  if (l < TAGS) out[(size_t)t * TAGS + l] = logit - m - logf(s);
}

// ---------------- launch ----------------
extern "C" void kernel_launch(void* const* d_in, const int* in_sizes, int n_in,
                              void* d_out, int out_size, void* d_ws, size_t ws_size,
                              hipStream_t stream) {
  const int*   ci    = (const int*)d_in[0];
  const int*   wi    = (const int*)d_in[1];
  const float* cemb  = (const float*)d_in[2];
  const float* wemb  = (const float*)d_in[3];
  const float* convw = (const float*)d_in[4];
  const float* convb = (const float*)d_in[5];
  const float* wih   = (const float*)d_in[6];
  const float* whh   = (const float*)d_in[7];
  const float* bih   = (const float*)d_in[8];
  const float* bhh   = (const float*)d_in[9];
  const float* dw    = (const float*)d_in[10];
  const float* db    = (const float*)d_in[11];
  float* out = (float*)d_out;

  uint8_t* ws = (uint8_t*)d_ws;
  size_t off = 0;
  auto alloc = [&](size_t bytes) -> void* {
    void* p = ws + off;
    off += (bytes + 255) & ~(size_t)255;
    return p;
  };
  float*    wt    = (float*)alloc((size_t)KPAD * NPAD * 4);
  float*    bsum  = (float*)alloc(NPAD * 4);
  uint32_t* wpack = (uint32_t*)alloc((size_t)4 * 128 * 256 * 4);
  float*    dwt   = (float*)alloc((size_t)HID * 64 * 4);
  float*    x     = (float*)alloc((size_t)NUM_WORDS * KPAD * 4);
  float*    pre   = (float*)alloc((size_t)NUM_WORDS * NPAD * 4);
  float*    hs    = (float*)alloc((size_t)NUM_WORDS * 256 * 4);
  uint64_t* gx    = (uint64_t*)alloc((size_t)2 * NPAD * 8);
  (void)ws_size; (void)in_sizes; (void)n_in; (void)out_size;

  hipMemsetAsync(gx, 0, (size_t)2 * NPAD * 8, stream);
  prep_wt<<<(KPAD * NPAD + 255) / 256, 256, 0, stream>>>(wih, wt);
  prep_bsum<<<(NPAD + 255) / 256, 256, 0, stream>>>(bih, bhh, bsum);
  prep_whh4<<<(4 * 128 * 256 + 255) / 256, 256, 0, stream>>>(whh, wpack);
  prep_dwt<<<(HID * 64 + 255) / 256, 256, 0, stream>>>(dw, dwt);
  feat_kernel<<<NUM_WORDS, 64, 0, stream>>>(ci, wi, cemb, wemb, convw, convb, x);
  gemm_pre<<<dim3(NPAD / GBN, NUM_WORDS / GBM), 256, 0, stream>>>(x, wt, bsum, pre);

  lstm4<<<4, 256, 0, stream>>>(wpack, pre, gx, hs);
  dense_kernel<<<NUM_WORDS / 4, 256, 0, stream>>>(hs, dwt, db, out);
}

// Round 4
// 6138.899 us; speedup vs baseline: 1.2994x; 1.2994x over previous
//
#include <hip/hip_runtime.h>
#include <hip/hip_fp16.h>
#include <cstdint>

// ---------------- sizes ----------------
#define NUM_WORDS 4096
#define MAX_CHARS 16
#define CE 10
#define NF 32
#define WE 250
#define HID 250
#define IN_DIM 282      // 32 + 250
#define KPAD 288        // padded IN_DIM
#define NGATE 1000      // 4*HID
#define NPAD 1024       // padded gate rows
#define TAGS 50

#define NBLK 8          // LSTM blocks
#define UPB 32          // hidden units per block (256 padded units)
#define ROWS 128        // gate-rows per block (4 gates x 32 units)
#define WSTRIDE 132     // padded u32 row stride in LDS (528 B, 16B-aligned, bank-spread)

typedef _Float16 half2v __attribute__((ext_vector_type(2)));

#ifndef __has_builtin
#define __has_builtin(x) 0
#endif

__device__ __forceinline__ float dot2acc(uint32_t w, uint32_t h, float acc) {
#if __has_builtin(__builtin_amdgcn_fdot2)
  return __builtin_amdgcn_fdot2(__builtin_bit_cast(half2v, w),
                                __builtin_bit_cast(half2v, h), acc, false);
#else
  half2v wv = __builtin_bit_cast(half2v, w);
  half2v hv = __builtin_bit_cast(half2v, h);
  return acc + (float)wv.x * (float)hv.x + (float)wv.y * (float)hv.y;
#endif
}

__device__ __forceinline__ uint64_t AL(const uint64_t* p) {
  return __hip_atomic_load(p, __ATOMIC_RELAXED, __HIP_MEMORY_SCOPE_AGENT);
}
__device__ __forceinline__ void AS(uint64_t* p, uint64_t v) {
  __hip_atomic_store(p, v, __ATOMIC_RELAXED, __HIP_MEMORY_SCOPE_AGENT);
}

// ---------------- prep kernels ----------------
__global__ void prep_wt(const float* __restrict__ wih, float* __restrict__ wt) {
  int idx = blockIdx.x * 256 + threadIdx.x;           // over [KPAD][NPAD]
  if (idx >= KPAD * NPAD) return;
  int k = idx >> 10, j = idx & (NPAD - 1);
  wt[idx] = (j < NGATE && k < IN_DIM) ? wih[j * IN_DIM + k] : 0.0f;
}

__global__ void prep_bsum(const float* __restrict__ bih, const float* __restrict__ bhh,
                          float* __restrict__ bsum) {
  int j = blockIdx.x * 256 + threadIdx.x;
  if (j >= NPAD) return;
  bsum[j] = (j < NGATE) ? bih[j] + bhh[j] : 0.0f;
}

// w_hh f32 -> f16x2 packed per LSTM block: wpack[b][r][c], r = gate*32 + u (unit=32b+u),
// c = u32 col (h halves 2c, 2c+1). Zero for pad units/cols.
__global__ void prep_whh8(const float* __restrict__ whh, uint32_t* __restrict__ wpack) {
  int idx = blockIdx.x * 256 + threadIdx.x;  // over NBLK*ROWS*128
  if (idx >= NBLK * ROWS * 128) return;
  int c = idx & 127, r = (idx >> 7) & 127, b = idx >> 14;
  int gt = r >> 5, u = r & 31, unit = UPB * b + u;
  int c0 = 2 * c, c1 = 2 * c + 1;
  float f0 = 0.0f, f1 = 0.0f;
  if (unit < HID) {
    int j = 250 * gt + unit;
    if (c0 < HID) f0 = whh[j * HID + c0];
    if (c1 < HID) f1 = whh[j * HID + c1];
  }
  wpack[idx] = (uint32_t)__half_as_ushort(__float2half(f0))
             | ((uint32_t)__half_as_ushort(__float2half(f1)) << 16);
}

__global__ void prep_dwt(const float* __restrict__ dw, float* __restrict__ dwt) {
  int idx = blockIdx.x * 256 + threadIdx.x;    // over [HID][64]
  if (idx >= HID * 64) return;
  int k = idx >> 6, l = idx & 63;
  dwt[idx] = (l < TAGS) ? dw[l * HID + k] : 0.0f;
}

// ---------------- feature kernel: char CNN + word emb -> x[4096][288] ----------------
__global__ void feat_kernel(const int* __restrict__ ci, const int* __restrict__ wi,
                            const float* __restrict__ cemb, const float* __restrict__ wemb,
                            const float* __restrict__ convw, const float* __restrict__ convb,
                            float* __restrict__ x) {
  int w = blockIdx.x;
  int t = threadIdx.x;  // 64
  __shared__ float ce[MAX_CHARS][CE];
  __shared__ float cw[NF * CE * 3];
  for (int i = t; i < MAX_CHARS * CE; i += 64) {
    int ch = i / CE, d = i % CE;
    ce[ch][d] = cemb[ci[w * MAX_CHARS + ch] * CE + d];
  }
  for (int i = t; i < NF * CE * 3; i += 64) cw[i] = convw[i];
  __syncthreads();

  int f = t & 31, hf = t >> 5;
  float mx = -1e30f;
  for (int p = hf * 8; p < hf * 8 + 8; ++p) {
    float s = 0.0f;
    for (int kk = 0; kk < 3; ++kk) {
      int cp = p + kk - 1;
      if (cp < 0 || cp > 15) continue;
      for (int d = 0; d < CE; ++d) s = fmaf(ce[cp][d], cw[f * 30 + d * 3 + kk], s);
    }
    mx = fmaxf(mx, s);
  }
  float other = __shfl_xor(mx, 32, 64);
  mx = fmaxf(mx, other) + convb[f];
  if (t < 32) x[(size_t)w * KPAD + f] = mx;

  int widx = wi[w];
  for (int d = t; d < WE; d += 64) x[(size_t)w * KPAD + 32 + d] = wemb[(size_t)widx * WE + d];
  if (t < KPAD - IN_DIM) x[(size_t)w * KPAD + IN_DIM + t] = 0.0f;
}

// ---------------- pre-gate GEMM: pre[4096][1024] = x[4096][288] * wt[288][1024] + bsum ----
#define GBM 64
#define GBN 64
#define GBK 16
__global__ __launch_bounds__(256) void gemm_pre(const float* __restrict__ x,
                                                const float* __restrict__ wt,
                                                const float* __restrict__ bsum,
                                                float* __restrict__ pre) {
  __shared__ float As[GBK][GBM];
  __shared__ float Bs[GBK][GBN];
  int tid = threadIdx.x;
  int m0 = blockIdx.y * GBM, n0 = blockIdx.x * GBN;
  int tx = tid & 15, ty = tid >> 4;
  float acc[4][4] = {};
  for (int k0 = 0; k0 < KPAD; k0 += GBK) {
    {
      int r = tid >> 2, cq = (tid & 3) * 4;
      float4 av = *(const float4*)(x + (size_t)(m0 + r) * KPAD + k0 + cq);
      As[cq + 0][r] = av.x; As[cq + 1][r] = av.y; As[cq + 2][r] = av.z; As[cq + 3][r] = av.w;
    }
    {
      int r = tid >> 4, c = (tid & 15) * 4;
      float4 bv = *(const float4*)(wt + (size_t)(k0 + r) * NPAD + n0 + c);
      *(float4*)&Bs[r][c] = bv;
    }
    __syncthreads();
#pragma unroll
    for (int k = 0; k < GBK; ++k) {
      float a[4], b[4];
#pragma unroll
      for (int i = 0; i < 4; ++i) a[i] = As[k][ty * 4 + i];
#pragma unroll
      for (int j = 0; j < 4; ++j) b[j] = Bs[k][tx * 4 + j];
#pragma unroll
      for (int i = 0; i < 4; ++i)
#pragma unroll
        for (int j = 0; j < 4; ++j) acc[i][j] = fmaf(a[i], b[j], acc[i][j]);
    }
    __syncthreads();
  }
#pragma unroll
  for (int i = 0; i < 4; ++i) {
    int m = m0 + ty * 4 + i;
#pragma unroll
    for (int j = 0; j < 4; ++j) {
      int n = n0 + tx * 4 + j;
      pre[(size_t)m * NPAD + n] = acc[i][j] + bsum[n];
    }
  }
}

// ---------------- 8-block LSTM, unit-split, LDS-resident weights ----------------
// Block b owns hidden units [32b, 32b+32): all 4 gates locally -> only h is exchanged.
// Thread t: gate-row r = ((t>>5)&3)*32 + (t&31), K-half kh = t>>7; 64 dot2 from LDS.
// Wave0 does combine+act+c/h+publish (no intra-phase barriers); threads 64..175 poll
// the 112 remote tagged words. LDS weights: no per-thread arrays -> no spill risk.
__global__ __launch_bounds__(256, 1) void lstm8(const uint32_t* __restrict__ wpack,
                                                const float* __restrict__ pre,
                                                uint64_t* __restrict__ gx,
                                                float* __restrict__ hs) {
  extern __shared__ uint8_t smem[];
  uint32_t* s_w    = (uint32_t*)smem;                           // [128][132] u32
  float*    s_part = (float*)(smem + ROWS * WSTRIDE * 4);       // [256]
  float*    s_act  = s_part + 256;                              // [128]
  uint32_t* s_h2   = (uint32_t*)(s_act + 128);                  // [2][128]

  const int b = blockIdx.x;
  const int t = threadIdx.x;

  // ---- stage weights into LDS ----
  {
    int r = t >> 1, half = t & 1;
    const uint4* src = (const uint4*)(wpack + (size_t)b * ROWS * 128) + r * 32 + half * 16;
    uint4* dst = (uint4*)&s_w[r * WSTRIDE + half * 64];
#pragma unroll
    for (int i = 0; i < 16; ++i) dst[i] = src[i];
  }
  if (t < 128) { s_h2[t] = 0u; s_h2[128 + t] = 0u; }
  __syncthreads();

  const int r  = ((t >> 5) & 3) * 32 + (t & 31);
  const int kh = t >> 7;
  const uint4* wv4 = (const uint4*)&s_w[r * WSTRIDE + kh * 64];

  // wave0 per-lane state (lanes 0..63 handle rows t and t+64)
  float cst = 0.0f;
  int colA = 0, colB = 0;
  float pvA = 0.0f, pvB = 0.0f;
  if (t < 64) {
    colA = 250 * (t >> 5) + UPB * b + (t & 31);            // gt in {0,1}
    colB = 250 * ((t + 64) >> 5) + UPB * b + (t & 31);     // gt in {2,3}
    pvA = pre[colA];
    pvB = pre[colB];
  }

#pragma unroll 1
  for (int step = 0; step < NUM_WORDS; ++step) {
    const int p2 = step & 1;
    const int p2n = p2 ^ 1;
    const uint32_t tag = (uint32_t)(step + 1);
    const uint4* hv4 = (const uint4*)&s_h2[p2 * 128 + kh * 64];

    // ---- K-half dot: 64 dot2 per thread, weights lane-spread, h broadcast ----
    float a0 = 0.0f, a1 = 0.0f, a2 = 0.0f, a3 = 0.0f;
#pragma unroll
    for (int q = 0; q < 16; ++q) {
      uint4 wv = wv4[q];
      uint4 hv = hv4[q];
      a0 = dot2acc(wv.x, hv.x, a0);
      a1 = dot2acc(wv.y, hv.y, a1);
      a2 = dot2acc(wv.z, hv.z, a2);
      a3 = dot2acc(wv.w, hv.w, a3);
    }
    s_part[t] = (a0 + a1) + (a2 + a3);
    __syncthreads();

    if (t < 64) {
      // combine both K-halves for rows t and t+64, add pre-gates
      float aA = s_part[t] + s_part[t + 128] + pvA;
      float aB = s_part[t + 64] + s_part[t + 192] + pvB;
      if (step + 1 < NUM_WORDS) {
        pvA = pre[(size_t)(step + 1) * NPAD + colA];
        pvB = pre[(size_t)(step + 1) * NPAD + colB];
      }
      // rows t: gates i/f -> sigmoid; rows t+64: gate g (lanes<32) tanh, gate o sigmoid
      float zA = __expf(-aA);
      float actA = 1.0f / (1.0f + zA);
      bool tB = ((t + 64) >> 5) == 2;
      float zB = __expf(tB ? 2.0f * aB : -aB);
      float invB = 1.0f / (1.0f + zB);
      float actB = tB ? 1.0f - 2.0f * invB : invB;
      s_act[t] = actA;
      s_act[t + 64] = actB;
      // c/h for this block's 32 units (same wave: LDS ops are in-order)
      float hA = 0.0f;
      if (t < 32) {
        float gi = s_act[t], gf = s_act[32 + t], gg = s_act[64 + t], go = s_act[96 + t];
        cst = gf * cst + gi * gg;
        float z2 = __expf(2.0f * cst);
        float th = 1.0f - 2.0f / (1.0f + z2);
        hA = go * th;
        hs[(size_t)step * 256 + UPB * b + t] = hA;
      }
      // pack pairs and publish 16 tagged words (fire-and-forget)
      float h0 = __shfl(hA, 2 * (t & 15), 64);
      float h1 = __shfl(hA, 2 * (t & 15) + 1, 64);
      if (t < 16) {
        uint32_t pay = (uint32_t)__half_as_ushort(__float2half(h0))
                     | ((uint32_t)__half_as_ushort(__float2half(h1)) << 16);
        AS(&gx[(size_t)p2n * 128 + b * 16 + t], ((uint64_t)tag << 32) | (uint64_t)pay);
        s_h2[p2n * 128 + b * 16 + t] = pay;
      }
    } else if (t < 176) {
      // poll one remote word each (112 = 7 blocks x 16 words)
      int p = t - 64;
      int rw = (p < b * 16) ? p : p + 16;
      uint64_t v = AL(&gx[(size_t)p2n * 128 + rw]);
      while ((uint32_t)(v >> 32) != tag) v = AL(&gx[(size_t)p2n * 128 + rw]);
      s_h2[p2n * 128 + rw] = (uint32_t)v;
    }
    __syncthreads();   // s_h2[p2n] complete before next step's dots
  }
}

// ---------------- dense + log_softmax ----------------
__global__ __launch_bounds__(256) void dense_kernel(const float* __restrict__ hs,
                                                    const float* __restrict__ dwt,
                                                    const float* __restrict__ db,
                                                    float* __restrict__ out) {
  int t = blockIdx.x * 4 + (threadIdx.x >> 6);
  int l = threadIdx.x & 63;
  float acc = 0.0f;
  for (int k = 0; k < HID; ++k) acc = fmaf(hs[(size_t)t * 256 + k], dwt[k * 64 + l], acc);
  float logit = acc + ((l < TAGS) ? db[l] : 0.0f);
  float val = (l < TAGS) ? logit : -1e30f;
  float m = val;
#pragma unroll
  for (int off = 32; off; off >>= 1) m = fmaxf(m, __shfl_xor(m, off, 64));
  float e = (l < TAGS) ? __expf(logit - m) : 0.0f;
  float s = e;
#pragma unroll
  for (int off = 32; off; off >>= 1) s += __shfl_xor(s, off, 64);
  if (l < TAGS) out[(size_t)t * TAGS + l] = logit - m - logf(s);
}

// ---------------- launch ----------------
extern "C" void kernel_launch(void* const* d_in, const int* in_sizes, int n_in,
                              void* d_out, int out_size, void* d_ws, size_t ws_size,
                              hipStream_t stream) {
  const int*   ci    = (const int*)d_in[0];
  const int*   wi    = (const int*)d_in[1];
  const float* cemb  = (const float*)d_in[2];
  const float* wemb  = (const float*)d_in[3];
  const float* convw = (const float*)d_in[4];
  const float* convb = (const float*)d_in[5];
  const float* wih   = (const float*)d_in[6];
  const float* whh   = (const float*)d_in[7];
  const float* bih   = (const float*)d_in[8];
  const float* bhh   = (const float*)d_in[9];
  const float* dw    = (const float*)d_in[10];
  const float* db    = (const float*)d_in[11];
  float* out = (float*)d_out;

  uint8_t* ws = (uint8_t*)d_ws;
  size_t off = 0;
  auto alloc = [&](size_t bytes) -> void* {
    void* p = ws + off;
    off += (bytes + 255) & ~(size_t)255;
    return p;
  };
  float*    wt    = (float*)alloc((size_t)KPAD * NPAD * 4);
  float*    bsum  = (float*)alloc(NPAD * 4);
  uint32_t* wpack = (uint32_t*)alloc((size_t)NBLK * ROWS * 128 * 4);
  float*    dwt   = (float*)alloc((size_t)HID * 64 * 4);
  float*    x     = (float*)alloc((size_t)NUM_WORDS * KPAD * 4);
  float*    pre   = (float*)alloc((size_t)NUM_WORDS * NPAD * 4);
  float*    hs    = (float*)alloc((size_t)NUM_WORDS * 256 * 4);
  uint64_t* gx    = (uint64_t*)alloc((size_t)2 * 128 * 8);
  (void)ws_size; (void)in_sizes; (void)n_in; (void)out_size;

  hipMemsetAsync(gx, 0, (size_t)2 * 128 * 8, stream);
  prep_wt<<<(KPAD * NPAD + 255) / 256, 256, 0, stream>>>(wih, wt);
  prep_bsum<<<(NPAD + 255) / 256, 256, 0, stream>>>(bih, bhh, bsum);
  prep_whh8<<<(NBLK * ROWS * 128 + 255) / 256, 256, 0, stream>>>(whh, wpack);
  prep_dwt<<<(HID * 64 + 255) / 256, 256, 0, stream>>>(dw, dwt);
  feat_kernel<<<NUM_WORDS, 64, 0, stream>>>(ci, wi, cemb, wemb, convw, convb, x);
  gemm_pre<<<dim3(NPAD / GBN, NUM_WORDS / GBM), 256, 0, stream>>>(x, wt, bsum, pre);

  size_t smem = (size_t)ROWS * WSTRIDE * 4 + 256 * 4 + 128 * 4 + 2 * 128 * 4;
  hipFuncSetAttribute((const void*)lstm8,
                      hipFuncAttributeMaxDynamicSharedMemorySize, (int)smem);
  lstm8<<<NBLK, 256, smem, stream>>>(wpack, pre, gx, hs);
  dense_kernel<<<NUM_WORDS / 4, 256, 0, stream>>>(hs, dwt, db, out);
}